// Round 7
// baseline (516.217 us; speedup 1.0000x reference)
//
#include <hip/hip_runtime.h>
#include <hip/hip_bf16.h>
#include <cstdint>
#include <cstddef>

typedef __bf16 bf16;
typedef __attribute__((ext_vector_type(8))) __bf16 bf16x8;
typedef __attribute__((ext_vector_type(4))) float f32x4;
typedef __attribute__((ext_vector_type(16))) float f32x16;
typedef __attribute__((ext_vector_type(4))) int i32x4;
typedef __attribute__((address_space(3))) const bf16* lds_cp;

#define B_SZ  8192
#define NAGENT 8
#define NA_N  16
#define OBS_DD 2048
#define ACT_DD 128
#define IN_DD 2176
#define H1_D  1024
#define H2_D  1024

#define BM 256
#define BN 256
#define BK 64
#define GRID_M (B_SZ / BM)   // 32
#define GRID_N (1024 / BN)   // 4

__device__ __forceinline__ void gload16(const void* g, void* l) {
    __builtin_amdgcn_global_load_lds(
        (__attribute__((address_space(1))) void*)(g),
        (__attribute__((address_space(3))) void*)(l), 16, 0, 0);
}

#define MFMA32(a, b, c) __builtin_amdgcn_mfma_f32_32x32x16_bf16((a), (b), (c), 0, 0, 0)
#define BC(x) __builtin_bit_cast(bf16x8, x)

// ---------- preprocessing (verified rounds 1-6) ----------

__global__ void k_convert_x(const float* __restrict__ obs,
                            const float* __restrict__ act,
                            bf16* __restrict__ xb) {
    const int chunks = IN_DD / 8;          // 272
    int idx = blockIdx.x * blockDim.x + threadIdx.x;
    if (idx >= B_SZ * chunks) return;
    int b = idx / chunks;
    int c8 = idx - b * chunks;
    const float* src = (c8 < OBS_DD / 8)
        ? (obs + (size_t)b * OBS_DD + c8 * 8)
        : (act + (size_t)b * ACT_DD + (c8 - OBS_DD / 8) * 8);
    float4 v0 = ((const float4*)src)[0];
    float4 v1 = ((const float4*)src)[1];
    bf16x8 o;
    o[0] = (bf16)v0.x; o[1] = (bf16)v0.y; o[2] = (bf16)v0.z; o[3] = (bf16)v0.w;
    o[4] = (bf16)v1.x; o[5] = (bf16)v1.y; o[6] = (bf16)v1.z; o[7] = (bf16)v1.w;
    ((bf16x8*)(xb + (size_t)b * IN_DD))[c8] = o;
}

__global__ void k_transpose_w(const float* __restrict__ src, bf16* __restrict__ dst,
                              int K, int H, int maskStart) {
    __shared__ float tile[32][33];
    int a = blockIdx.z;
    int k0 = blockIdx.x * 32, h0 = blockIdx.y * 32;
    const float* s = src + (size_t)a * K * H;
    bf16* d = dst + (size_t)a * K * H;
    int tx = threadIdx.x, ty = threadIdx.y;
    #pragma unroll
    for (int i = 0; i < 32; i += 8) {
        int k = k0 + ty + i;
        float v = s[(size_t)k * H + h0 + tx];
        if (k >= maskStart) {
            int g = k - maskStart;
            if ((g >> 4) == a) v = 0.f;
        }
        tile[ty + i][tx] = v;
    }
    __syncthreads();
    #pragma unroll
    for (int i = 0; i < 32; i += 8) {
        d[(size_t)(h0 + ty + i) * K + k0 + tx] = (bf16)tile[tx][ty + i];
    }
}

__global__ void k_transpose_w3(const float* __restrict__ src, bf16* __restrict__ dst) {
    int idx = blockIdx.x * blockDim.x + threadIdx.x;
    if (idx >= NAGENT * NA_N * H2_D) return;
    int a = idx / (NA_N * H2_D);
    int n = (idx / H2_D) % NA_N;
    int k = idx % H2_D;
    dst[idx] = (bf16)src[(size_t)a * H2_D * NA_N + (size_t)k * NA_N + n];
}

// out[b, a*16+n] = b3[a,n]  (bias pre-init; fused L3 atomically accumulates)
__global__ void k_init_out(const float* __restrict__ b3, float* __restrict__ out) {
    int i = blockIdx.x * blockDim.x + threadIdx.x;
    if (i < B_SZ * NAGENT * NA_N) out[i] = b3[i & 127];
}

// ---------- 256x256x64 split-barrier pipelined GEMM, 32x32x16 engine ----------
// Slots (elems): A: (t&1)*16384 ; B: 32768 + (t&1)*16384. 128 KiB.
// Tile t: [G1G2(t) already in flight from tile t-1]
//   stage(t+1); lgkm(4)->C1; issue G3; lgkm(8)->C2; issue G4; lgkm(4)->C3;
//   vmcnt(0)+MID barrier (publishes slot t+1, covered by C1-C3);
//   issue G1G2(t+1) (hidden under C4); lgkm(12)->C4; END barrier (slot-t reuse).
#define DSR2(d0, d1, addr, O0, O1)                                      \
    asm volatile("ds_read_b128 %0, %2 offset:" #O0 "\n\t"               \
                 "ds_read_b128 %1, %2 offset:" #O1                      \
                 : "=&v"(d0), "=&v"(d1) : "v"(addr))

// 8 MFMAs: rows (M0,M1), cols n0/n1, k-halves A/B.
// A00=A(M0,ksA) A01=A(M0,ksB) A10=A(M1,ksA) A11=A(M1,ksB)
// B00=B(n0,ksA) B01=B(n0,ksB) B10=B(n1,ksA) B11=B(n1,ksB)
#define PH(M0, M1, A00, A01, A10, A11, B00, B01, B10, B11) do {         \
        acc[M0][0] = MFMA32(BC(A00), BC(B00), acc[M0][0]);              \
        acc[M0][1] = MFMA32(BC(A00), BC(B10), acc[M0][1]);              \
        acc[M1][0] = MFMA32(BC(A10), BC(B00), acc[M1][0]);              \
        acc[M1][1] = MFMA32(BC(A10), BC(B10), acc[M1][1]);              \
        acc[M0][0] = MFMA32(BC(A01), BC(B01), acc[M0][0]);              \
        acc[M0][1] = MFMA32(BC(A01), BC(B11), acc[M0][1]);              \
        acc[M1][0] = MFMA32(BC(A11), BC(B01), acc[M1][0]);              \
        acc[M1][1] = MFMA32(BC(A11), BC(B11), acc[M1][1]);              \
    } while (0)

template<int FUSE>
__global__ __launch_bounds__(512, 1)
void k_gemm256(const bf16* __restrict__ Ain, size_t aStride, int lda,
               const bf16* __restrict__ Bw, const float* __restrict__ bias,
               bf16* __restrict__ Cout, size_t cStride, int K,
               int aOff, int gridZ,
               const bf16* __restrict__ W3Tp, float* __restrict__ outp) {
    extern __shared__ bf16 lds[];   // 65536 elems = 128 KiB

    const int tid = threadIdx.x;
    const int w = tid >> 6;
    const int l = tid & 63;

    // XCD-chunked remap (nwg = 128*gridZ, % 8 == 0)
    int flat = blockIdx.x + GRID_M * (blockIdx.y + GRID_N * blockIdx.z);
    int q8 = (GRID_M * GRID_N * gridZ) >> 3;
    int lin2 = (flat & 7) * q8 + (flat >> 3);
    const int mt = lin2 % GRID_M;
    int rest = lin2 / GRID_M;
    const int ntile = rest % GRID_N;
    const int az = rest / GRID_N;
    const int aw = az + aOff;

    const int rowBase = mt * BM;
    const int colBase = ntile * BN;
    const bf16* Aag = Ain + (size_t)az * aStride;
    const bf16* Bag = Bw + (size_t)aw * (size_t)1024 * K;

    const int wr = (w >> 2) * 128;   // wave rows: 4 m-frags of 32
    const int wc = (w & 3) * 64;     // wave cols: 2 n-frags of 32
    const int r31 = l & 31;
    const int hi = l >> 5;
    const int x7 = l & 7;

    // 32x32x16 fragment addressing (r5-verified): row = base + (l&31),
    // logical k-chunk = ks*2 + hi, phys = logical ^ (row&7) = ^ (l&7).
    const int arow = (wr + r31) * 64;            // + m*2048 elems (4096 B)
    const int brow = (wc + r31) * 64;            // + n*2048 elems
    int cs[4];
    #pragma unroll
    for (int ks = 0; ks < 4; ++ks) cs[ks] = ((ks * 2 + hi) ^ x7) * 8;

    // staging (r3-verified): lane -> row w*16+(l>>3), pre-swizzled source col
    const int sRow = w * 16 + (l >> 3);
    const int sCol = ((l & 7) ^ (l >> 3)) * 8;
    const bf16* pA0 = Aag + (size_t)(rowBase + sRow) * lda + sCol;
    const bf16* pA1 = Aag + (size_t)(rowBase + 128 + sRow) * lda + sCol;
    const bf16* pB0 = Bag + (size_t)(colBase + sRow) * K + sCol;
    const bf16* pB1 = Bag + (size_t)(colBase + 128 + sRow) * K + sCol;
    const size_t l8a = (size_t)8 * lda;
    const size_t l8b = (size_t)8 * K;

    const int nkt = K / BK;

#define STAGE_A(t1, half) do {                                              \
        const bf16* g_ = ((half) ? pA1 : pA0) + (t1) * BK;                  \
        bf16* d_ = &lds[(((t1) & 1) * 16384) + (half) * 8192 + w * 1024];   \
        gload16(g_, d_);                                                    \
        gload16(g_ + l8a, d_ + 512);                                        \
    } while (0)
#define STAGE_B(t2, half) do {                                              \
        const bf16* g_ = ((half) ? pB1 : pB0) + (t2) * BK;                  \
        bf16* d_ = &lds[32768 + (((t2) & 1) * 16384) + (half) * 8192 + w * 1024]; \
        gload16(g_, d_);                                                    \
        gload16(g_ + l8b, d_ + 512);                                        \
    } while (0)

    f32x16 acc[4][2] = {};
    // frag regs: ra/rb (C1), rc (C2), re/rd (C3), rf (C4)
    i32x4 ra0, ra1, ra2, ra3, rb0, rb1, rb2, rb3;
    i32x4 rc0, rc1, rc2, rc3, rd0, rd1, rd2, rd3;
    i32x4 re0, re1, re2, re3, rf0, rf1, rf2, rf3;

    // prologue: stage tile 0, drain, publish; issue G1(0)+G2(0)
    STAGE_A(0, 0); STAGE_A(0, 1);
    STAGE_B(0, 0); STAGE_B(0, 1);
    asm volatile("s_waitcnt vmcnt(0)" ::: "memory");
    __builtin_amdgcn_s_barrier();
    {
        lds_cp A0 = (lds_cp)lds + (arow + cs[0]);
        lds_cp A1 = (lds_cp)lds + (arow + cs[1]);
        lds_cp Bb0 = (lds_cp)lds + (32768 + brow + cs[0]);
        lds_cp Bb1 = (lds_cp)lds + (32768 + brow + cs[1]);
        DSR2(ra0, ra1, A0, 0, 4096);        // A m0,m1 @ ks0
        DSR2(ra2, ra3, A1, 0, 4096);        // A m0,m1 @ ks1
        DSR2(rb0, rb1, Bb0, 0, 4096);       // B n0,n1 @ ks0
        DSR2(rb2, rb3, Bb1, 0, 4096);       // B n0,n1 @ ks1
        DSR2(rc0, rc1, A0, 8192, 12288);    // A m2,m3 @ ks0
        DSR2(rc2, rc3, A1, 8192, 12288);    // A m2,m3 @ ks1
    }

    for (int t = 0; t < nkt; ++t) {
        const int aS = (t & 1) * 16384;
        const int bS = 32768 + aS;
        lds_cp A2 = (lds_cp)lds + (aS + arow + cs[2]);
        lds_cp A3 = (lds_cp)lds + (aS + arow + cs[3]);
        lds_cp B2 = (lds_cp)lds + (bS + brow + cs[2]);
        lds_cp B3 = (lds_cp)lds + (bS + brow + cs[3]);
        const bool nxt = (t + 1 < nkt);

        if (nxt) {  // stage next tile early (drained at MID barrier, ~3 clusters away)
            STAGE_A(t + 1, 0); STAGE_A(t + 1, 1);
            STAGE_B(t + 1, 0); STAGE_B(t + 1, 1);
        }

        // C1: m0,m1 x ks0,ks1   [G1 done; G2(4) outstanding]
        asm volatile("s_waitcnt lgkmcnt(4)" ::: "memory");
        __builtin_amdgcn_sched_barrier(0);
        __builtin_amdgcn_s_setprio(1);
        PH(0, 1, ra0, ra2, ra1, ra3, rb0, rb2, rb1, rb3);
        __builtin_amdgcn_s_setprio(0);

        // G3: A m0,m1 @ ks2,ks3 + B @ ks2,ks3  (8 reads)
        DSR2(re0, re1, A2, 0, 4096);
        DSR2(re2, re3, A3, 0, 4096);
        DSR2(rd0, rd1, B2, 0, 4096);
        DSR2(rd2, rd3, B3, 0, 4096);

        // C2: m2,m3 x ks0,ks1   [G2 done; G3(8) outstanding]
        asm volatile("s_waitcnt lgkmcnt(8)" ::: "memory");
        __builtin_amdgcn_sched_barrier(0);
        __builtin_amdgcn_s_setprio(1);
        PH(2, 3, rc0, rc2, rc1, rc3, rb0, rb2, rb1, rb3);
        __builtin_amdgcn_s_setprio(0);

        // G4: A m2,m3 @ ks2,ks3  (4 reads)
        DSR2(rf0, rf1, A2, 8192, 12288);
        DSR2(rf2, rf3, A3, 8192, 12288);

        // C3: m0,m1 x ks2,ks3   [G3 done; G4(4) outstanding]
        asm volatile("s_waitcnt lgkmcnt(4)" ::: "memory");
        __builtin_amdgcn_sched_barrier(0);
        __builtin_amdgcn_s_setprio(1);
        PH(0, 1, re0, re2, re1, re3, rd0, rd2, rd1, rd3);
        __builtin_amdgcn_s_setprio(0);

        // MID barrier: stage(t+1) landed (covered by C1-C3); publish slot t+1
        asm volatile("s_waitcnt vmcnt(0)" ::: "memory");
        __builtin_amdgcn_s_barrier();

        if (nxt) {
            // G1(t+1)+G2(t+1): hidden under C4
            const int aS2 = ((t + 1) & 1) * 16384;
            const int bS2 = 32768 + aS2;
            lds_cp nA0 = (lds_cp)lds + (aS2 + arow + cs[0]);
            lds_cp nA1 = (lds_cp)lds + (aS2 + arow + cs[1]);
            lds_cp nB0 = (lds_cp)lds + (bS2 + brow + cs[0]);
            lds_cp nB1 = (lds_cp)lds + (bS2 + brow + cs[1]);
            DSR2(ra0, ra1, nA0, 0, 4096);
            DSR2(ra2, ra3, nA1, 0, 4096);
            DSR2(rb0, rb1, nB0, 0, 4096);
            DSR2(rb2, rb3, nB1, 0, 4096);
            DSR2(rc0, rc1, nA0, 8192, 12288);
            DSR2(rc2, rc3, nA1, 8192, 12288);
            // C4: m2,m3 x ks2,ks3   [G4 done; G1'G2'(12) outstanding]
            asm volatile("s_waitcnt lgkmcnt(12)" ::: "memory");
        } else {
            asm volatile("s_waitcnt lgkmcnt(0)" ::: "memory");
        }
        __builtin_amdgcn_sched_barrier(0);
        __builtin_amdgcn_s_setprio(1);
        PH(2, 3, rf0, rf2, rf1, rf3, rd0, rd2, rd1, rd3);
        __builtin_amdgcn_s_setprio(0);

        // END barrier: all waves' slot-t reads done before stage(t+2) reuses it
        __builtin_amdgcn_s_barrier();
    }
#undef STAGE_A
#undef STAGE_B

    // ---- epilogue: bias + relu -> swizzled C-LDS tile [256][256] bf16 (r5-verified)
    __syncthreads();
    const float* bAg = bias + (size_t)aw * 1024;
    float bb2[2];
    #pragma unroll
    for (int n = 0; n < 2; ++n) bb2[n] = bAg[colBase + wc + n * 32 + r31];
    #pragma unroll
    for (int m = 0; m < 4; ++m)
        #pragma unroll
        for (int n = 0; n < 2; ++n)
            #pragma unroll
            for (int r = 0; r < 16; ++r) {
                float v = acc[m][n][r] + bb2[n];
                v = fmaxf(v, 0.f);
                int row = wr + m * 32 + (r & 3) + 8 * (r >> 2) + 4 * hi;
                int col = wc + n * 32 + r31;
                lds[row * 256 + ((((col >> 3) ^ (row & 7)) << 3) | (col & 7))] = (bf16)v;
            }
    __syncthreads();

    if constexpr (!FUSE) {
        bf16* Cg = Cout + (size_t)az * cStride + (size_t)rowBase * 1024 + colBase;
        const int er = tid >> 5;
        const int ec = tid & 31;
        #pragma unroll
        for (int i = 0; i < 16; ++i) {
            int row = i * 16 + er;
            int phys = ec ^ (row & 7);
            *(bf16x8*)&Cg[(size_t)row * 1024 + ec * 8] =
                *(const bf16x8*)&lds[row * 256 + phys * 8];
        }
    } else {
        // fused L3 (r3-verified): h2 tile x W3T[aw] -> atomicAdd into out
        const bf16* w3a = W3Tp + (size_t)aw * NA_N * H2_D;
        f32x4 oacc[2] = {};
        const int lr = l & 15, lq = l >> 4;
        const int frow0 = w * 32;
        #pragma unroll
        for (int ks = 0; ks < 8; ++ks) {
            bf16x8 bfrag = *(const bf16x8*)&w3a[(size_t)lr * H2_D + colBase + ks * 32 + lq * 8];
            #pragma unroll
            for (int mm = 0; mm < 2; ++mm) {
                int row = frow0 + mm * 16 + lr;
                int lc = (ks * 4 + lq) ^ (row & 7);
                bf16x8 afrag = *(const bf16x8*)&lds[row * 256 + lc * 8];
                oacc[mm] = __builtin_amdgcn_mfma_f32_16x16x32_bf16(afrag, bfrag, oacc[mm], 0, 0, 0);
            }
        }
        #pragma unroll
        for (int mm = 0; mm < 2; ++mm)
            #pragma unroll
            for (int r = 0; r < 4; ++r)
                atomicAdd(&outp[(size_t)(rowBase + frow0 + mm * 16 + lq * 4 + r) * 128
                                + aw * NA_N + lr], oacc[mm][r]);
    }
}

// ---------- launcher ----------
extern "C" void kernel_launch(void* const* d_in, const int* in_sizes, int n_in,
                              void* d_out, int out_size, void* d_ws, size_t ws_size,
                              hipStream_t stream) {
    const float* obs = (const float*)d_in[0];
    const float* act = (const float*)d_in[1];
    const float* W1 = (const float*)d_in[2];
    const float* b1 = (const float*)d_in[3];
    const float* W2 = (const float*)d_in[4];
    const float* b2 = (const float*)d_in[5];
    const float* W3 = (const float*)d_in[6];
    const float* b3 = (const float*)d_in[7];
    float* out = (float*)d_out;

    const size_t SZ_XB  = (size_t)B_SZ * IN_DD * 2;
    const size_t SZ_W1T = (size_t)NAGENT * H1_D * IN_DD * 2;
    const size_t SZ_W2T = (size_t)NAGENT * H1_D * H2_D * 2;
    const size_t SZ_W3T = (size_t)NAGENT * NA_N * H2_D * 2;
    const size_t SZ_H1  = (size_t)B_SZ * H1_D * 2;
    const size_t SZ_FIX = SZ_XB + SZ_W1T + SZ_W2T + SZ_W3T;

    char* ws = (char*)d_ws;
    bf16* Xb  = (bf16*)ws;
    bf16* W1T = (bf16*)(ws + SZ_XB);
    bf16* W2T = (bf16*)(ws + SZ_XB + SZ_W1T);
    bf16* W3T = (bf16*)(ws + SZ_XB + SZ_W1T + SZ_W2T);
    char* hbase = ws + SZ_FIX;

    // largest G (agents per pass) that fits: h1 only (h2/L3 fused)
    int G = 8;
    while (G > 1 && ws_size < SZ_FIX + (size_t)G * SZ_H1) G >>= 1;

    (void)hipFuncSetAttribute((const void*)k_gemm256<0>,
                              hipFuncAttributeMaxDynamicSharedMemorySize, 131072);
    (void)hipFuncSetAttribute((const void*)k_gemm256<1>,
                              hipFuncAttributeMaxDynamicSharedMemorySize, 131072);

    // out = b3 broadcast (fused L3 accumulates on top)
    k_init_out<<<(B_SZ * 128 + 255) / 256, 256, 0, stream>>>(b3, out);

    // preprocessing
    {
        int n = B_SZ * (IN_DD / 8);
        k_convert_x<<<(n + 255) / 256, 256, 0, stream>>>(obs, act, Xb);
    }
    k_transpose_w<<<dim3(IN_DD / 32, H1_D / 32, NAGENT), dim3(32, 8), 0, stream>>>(
        W1, W1T, IN_DD, H1_D, OBS_DD);
    k_transpose_w<<<dim3(H1_D / 32, H2_D / 32, NAGENT), dim3(32, 8), 0, stream>>>(
        W2, W2T, H1_D, H2_D, 1 << 30);
    {
        int n = NAGENT * NA_N * H2_D;
        k_transpose_w3<<<(n + 255) / 256, 256, 0, stream>>>(W3, W3T);
    }

    const size_t agElems = (size_t)B_SZ * H1_D;
    bf16* h1 = (bf16*)hbase;

    for (int g0 = 0; g0 < NAGENT; g0 += G) {
        k_gemm256<0><<<dim3(GRID_M, GRID_N, G), 512, 131072, stream>>>(
            Xb, 0, IN_DD, W1T, b1, h1, agElems, IN_DD, g0, G, nullptr, nullptr);
        k_gemm256<1><<<dim3(GRID_M, GRID_N, G), 512, 131072, stream>>>(
            h1, agElems, H1_D, W2T, b2, nullptr, 0, H1_D, g0, G, W3T, out);
    }
    (void)in_sizes; (void)n_in; (void)out_size;
}